// Round 3
// baseline (83.300 us; speedup 1.0000x reference)
//
#include <hip/hip_runtime.h>
#include <hip/hip_bf16.h>
#include <stdint.h>

typedef float f32x4 __attribute__((ext_vector_type(4)));
typedef __bf16 bf16x8 __attribute__((ext_vector_type(8)));
typedef unsigned short ushort8 __attribute__((ext_vector_type(8)));

#define N_TOK 128
#define OUT_F 8192
#define IN_F  8192
#define RANK  32

#define KSPLIT 8            // main-gemm k-split
#define KB    (IN_F / KSPLIT)   // 1024 per block
#define BK    64
#define NSTEP (KB / BK)         // 16
#define TSPLIT 8            // lora-t k-split

// workspace layout (bytes)
#define XB_OFF 0
#define TB_OFF ((size_t)N_TOK * IN_F * 2)                       // 2 MiB of bf16 x
#define PO_OFF (TB_OFF + (size_t)TSPLIT * N_TOK * RANK * 4)     // + 128 KiB t-partials
// pO: KSPLIT * 128 * 8192 f32 = 32 MiB

__device__ __forceinline__ unsigned short bf16r(float f) {
    uint32_t u = __float_as_uint(f);
    return (unsigned short)((u + 0x7FFFu + ((u >> 16) & 1u)) >> 16);
}

// ---------------- kernel A: x fp32 -> bf16 ----------------
__global__ __launch_bounds__(256) void cvt_x(const float* __restrict__ x,
                                             unsigned short* __restrict__ xb) {
    size_t i = ((size_t)blockIdx.x * 256 + threadIdx.x) * 8;
    float4 a = *(const float4*)(x + i);
    float4 b = *(const float4*)(x + i + 4);
    ushort8 o;
    o[0] = bf16r(a.x); o[1] = bf16r(a.y); o[2] = bf16r(a.z); o[3] = bf16r(a.w);
    o[4] = bf16r(b.x); o[5] = bf16r(b.y); o[6] = bf16r(b.z); o[7] = bf16r(b.w);
    *(ushort8*)(xb + i) = o;
}

// ---------------- kernel B: t-partials = x @ lora_B^T (k-split) ----------------
__global__ __launch_bounds__(256) void lora_t(const float* __restrict__ x,
                                              const float* __restrict__ lb,
                                              float* __restrict__ tB) {
    int mg = blockIdx.x >> 3, kc = blockIdx.x & 7;
    int r = threadIdx.x & 31, mi = threadIdx.x >> 5;
    int m = mg * 8 + mi;
    const float4* xp = (const float4*)(x + (size_t)m * IN_F + kc * (IN_F / TSPLIT));
    const float4* bp = (const float4*)(lb + (size_t)r * IN_F + kc * (IN_F / TSPLIT));
    float a0 = 0.f, a1 = 0.f, a2 = 0.f, a3 = 0.f;
#pragma unroll 4
    for (int i = 0; i < (IN_F / TSPLIT) / 4; ++i) {
        float4 xv = xp[i], bv = bp[i];
        a0 = fmaf(xv.x, bv.x, a0);
        a1 = fmaf(xv.y, bv.y, a1);
        a2 = fmaf(xv.z, bv.z, a2);
        a3 = fmaf(xv.w, bv.w, a3);
    }
    tB[(kc * N_TOK + m) * RANK + r] = (a0 + a1) + (a2 + a3);
}

// ---------------- decode: 32-bit packed (16 ternary codes) -> 8 dwords of bf16 pairs ----------------
// code c in {0,1,2}: bf16 bits {-1:0xBF80, 0:0x0000, +1:0x3F80}; c==3 (never occurs) -> junk.
__device__ __forceinline__ void decode16(uint32_t p, uint32_t d[8]) {
    const uint32_t HI = 0x403F00BFu;  // high-byte table (sel>=4 -> src0)
    const uint32_t LO = 0x00800080u;  // low-byte table  (sel<4  -> src1)
#pragma unroll
    for (int j = 0; j < 8; ++j) {
        uint32_t c0 = (p >> (4 * j)) & 3u;
        uint32_t c1 = (p >> (4 * j + 2)) & 3u;
        uint32_t t = c0 | (c1 << 16);
        uint32_t sel = (t | (t << 8)) + 0x04000400u;
        d[j] = __builtin_amdgcn_perm(HI, LO, sel);  // [lo(c0),hi(c0),lo(c1),hi(c1)]
    }
}

// ---------------- kernel C: main ternary GEMM (bf16 MFMA, k-split partials) ----------------
// weight_packed arrives as int32 on device (harness materializes integer inputs
// as int32): one int per original packed byte, value 0..255.
// grid = 64 n-tiles * KSPLIT, 256 threads (4 waves, 2x2 of 64x64 wave tiles)
__global__ __launch_bounds__(256) void ternary_gemm(const unsigned short* __restrict__ xb,
                                                    const int* __restrict__ wp,
                                                    float* __restrict__ pO) {
    __shared__ unsigned short xs[128][72];  // x tile   [m][k], stride 144 B
    __shared__ unsigned short ww[128][72];  // W tile   [n][k]
    const int tid = threadIdx.x;
    const int nb = blockIdx.x >> 3;
    const int ks = blockIdx.x & 7;
    const int n0 = nb * 128;
    const int k0 = ks * KB;
    const int lane = tid & 63;
    const int wid = tid >> 6;
    const int wr = wid >> 1, wc = wid & 1;

    // staging: thread covers rows (tid>>2) and (tid>>2)+64
    // x: 16 bf16 (32 B) per row-half; W: 4 packed "bytes" (int32 each) -> 16 bf16
    const int srow = tid >> 2;
    const int xcol = (tid & 3) * 16;  // in bf16 elems, 4 threads x 16 = 64 = BK
    const unsigned short* xg0 = xb + (size_t)srow * IN_F + k0 + xcol;
    const unsigned short* xg1 = xg0 + (size_t)64 * IN_F;
    const int pcol = (tid & 3) * 4;  // in int32 units (4 packed-bytes per thread)
    const int* pg0 = wp + (size_t)(n0 + srow) * (IN_F / 4) + (k0 >> 2) + pcol;
    const int* pg1 = pg0 + (size_t)64 * (IN_F / 4);

    f32x4 acc[4][4];
#pragma unroll
    for (int i = 0; i < 4; ++i)
#pragma unroll
        for (int j = 0; j < 4; ++j) acc[i][j] = (f32x4){0.f, 0.f, 0.f, 0.f};

    const int arow = lane & 15;
    const int kgrp = (lane >> 4) * 8;

    for (int s = 0; s < NSTEP; ++s) {
        uint4 xv0a = *(const uint4*)(xg0 + s * BK);
        uint4 xv0b = *(const uint4*)(xg0 + s * BK + 8);
        uint4 xv1a = *(const uint4*)(xg1 + s * BK);
        uint4 xv1b = *(const uint4*)(xg1 + s * BK + 8);
        int4 pv0 = *(const int4*)(pg0 + s * (BK / 4));
        int4 pv1 = *(const int4*)(pg1 + s * (BK / 4));
        uint32_t p0 = (uint32_t)(pv0.x & 0xFF) | ((uint32_t)(pv0.y & 0xFF) << 8) |
                      ((uint32_t)(pv0.z & 0xFF) << 16) | ((uint32_t)(pv0.w & 0xFF) << 24);
        uint32_t p1 = (uint32_t)(pv1.x & 0xFF) | ((uint32_t)(pv1.y & 0xFF) << 8) |
                      ((uint32_t)(pv1.z & 0xFF) << 16) | ((uint32_t)(pv1.w & 0xFF) << 24);
        uint32_t d0[8], d1[8];
        decode16(p0, d0);
        decode16(p1, d1);
        __syncthreads();  // previous tile fully consumed
        *(uint4*)&xs[srow][xcol] = xv0a;
        *(uint4*)&xs[srow][xcol + 8] = xv0b;
        *(uint4*)&xs[srow + 64][xcol] = xv1a;
        *(uint4*)&xs[srow + 64][xcol + 8] = xv1b;
        uint4* w0 = (uint4*)&ww[srow][(tid & 3) * 16];
        uint4* w1 = (uint4*)&ww[srow + 64][(tid & 3) * 16];
        w0[0] = make_uint4(d0[0], d0[1], d0[2], d0[3]);
        w0[1] = make_uint4(d0[4], d0[5], d0[6], d0[7]);
        w1[0] = make_uint4(d1[0], d1[1], d1[2], d1[3]);
        w1[1] = make_uint4(d1[4], d1[5], d1[6], d1[7]);
        __syncthreads();
#pragma unroll
        for (int kk = 0; kk < 2; ++kk) {
            const int kcol = kk * 32 + kgrp;
            bf16x8 af[4], bfr[4];
#pragma unroll
            for (int ar = 0; ar < 4; ++ar)
                af[ar] = *(const bf16x8*)&xs[wr * 64 + ar * 16 + arow][kcol];
#pragma unroll
            for (int br = 0; br < 4; ++br)
                bfr[br] = *(const bf16x8*)&ww[wc * 64 + br * 16 + arow][kcol];
#pragma unroll
            for (int ar = 0; ar < 4; ++ar)
#pragma unroll
                for (int br = 0; br < 4; ++br)
                    acc[ar][br] = __builtin_amdgcn_mfma_f32_16x16x32_bf16(
                        af[ar], bfr[br], acc[ar][br], 0, 0, 0);
        }
    }

    // epilogue: raw partial store (scale/lora/bias applied in reduce)
    float* po = pO + ((size_t)ks << 20);
    const int mrow = (lane >> 4) * 4;
#pragma unroll
    for (int ar = 0; ar < 4; ++ar) {
#pragma unroll
        for (int br = 0; br < 4; ++br) {
            int m = wr * 64 + ar * 16 + mrow;
            int n = n0 + wc * 64 + br * 16 + arow;
            float* pp = po + (size_t)m * OUT_F + n;
#pragma unroll
            for (int j = 0; j < 4; ++j) pp[(size_t)j * OUT_F] = acc[ar][br][j];
        }
    }
}

// ---------------- kernel D: reduce partials + scale + lora + bias ----------------
// grid = 32 n-blocks * 16 m-groups = 512 blocks; thread: one n, 8 m's
__global__ __launch_bounds__(256) void reduce_out(const float* __restrict__ pO,
                                                  const float* __restrict__ tB,
                                                  const float* __restrict__ scale,
                                                  const float* __restrict__ lora_A,
                                                  const float* __restrict__ bias,
                                                  float* __restrict__ out) {
    __shared__ float ts[8][RANK];
    int nb = blockIdx.x & 31, mg = blockIdx.x >> 5;
    int tid = threadIdx.x;
    int m0 = mg * 8;
    {
        int i = tid >> 5, r = tid & 31;
        float s = 0.f;
#pragma unroll
        for (int c = 0; c < TSPLIT; ++c) s += tB[(c * N_TOK + m0 + i) * RANK + r];
        ts[i][r] = s;
    }
    __syncthreads();
    int n = nb * 256 + tid;
    float sc = scale[n], bs = bias[n];
    float4 a4[8];
    const float4* ap = (const float4*)(lora_A + (size_t)n * RANK);
#pragma unroll
    for (int q = 0; q < 8; ++q) a4[q] = ap[q];
#pragma unroll
    for (int i = 0; i < 8; ++i) {
        int m = m0 + i;
        const float* pp = pO + (size_t)m * OUT_F + n;
        float s = 0.f;
#pragma unroll
        for (int c = 0; c < KSPLIT; ++c) s += pp[(size_t)c << 20];
        float l = 0.f;
#pragma unroll
        for (int q = 0; q < 8; ++q) {
            float4 tv = *(const float4*)&ts[i][q * 4];
            l = fmaf(tv.x, a4[q].x, l);
            l = fmaf(tv.y, a4[q].y, l);
            l = fmaf(tv.z, a4[q].z, l);
            l = fmaf(tv.w, a4[q].w, l);
        }
        out[(size_t)m * OUT_F + n] = fmaf(s, sc, l + bs);
    }
}

extern "C" void kernel_launch(void* const* d_in, const int* in_sizes, int n_in,
                              void* d_out, int out_size, void* d_ws, size_t ws_size,
                              hipStream_t stream) {
    const float* x      = (const float*)d_in[0];
    const int*   wp     = (const int*)d_in[1];   // uint8 input -> int32 on device
    const float* scale  = (const float*)d_in[2];
    const float* lora_A = (const float*)d_in[3];
    const float* lora_B = (const float*)d_in[4];
    const float* bias   = (const float*)d_in[5];
    float* out = (float*)d_out;

    char* ws = (char*)d_ws;
    unsigned short* xb = (unsigned short*)(ws + XB_OFF);
    float* tB = (float*)(ws + TB_OFF);
    float* pO = (float*)(ws + PO_OFF);

    cvt_x<<<(N_TOK * IN_F) / (256 * 8), 256, 0, stream>>>(x, xb);
    lora_t<<<16 * TSPLIT, 256, 0, stream>>>(x, lora_B, tB);
    ternary_gemm<<<(OUT_F / 128) * KSPLIT, 256, 0, stream>>>(xb, wp, pO);
    reduce_out<<<(OUT_F / 256) * (N_TOK / 8), 256, 0, stream>>>(pO, tB, scale, lora_A, bias, out);
}

// Round 4
// 61.532 us; speedup vs baseline: 1.3538x; 1.3538x over previous
//
#include <hip/hip_runtime.h>
#include <hip/hip_bf16.h>
#include <stdint.h>

typedef float f32x4 __attribute__((ext_vector_type(4)));
typedef __bf16 bf16x8 __attribute__((ext_vector_type(8)));
typedef unsigned short ushort8 __attribute__((ext_vector_type(8)));

#define N_TOK 128
#define OUT_F 8192
#define IN_F  8192
#define RANK  32

#define KSPLIT 16               // main-gemm k-split
#define KB    (IN_F / KSPLIT)   // 512 per block
#define BK    64
#define NSTEP (KB / BK)         // 8
#define LKC   4                 // lora-t k-chunks

// workspace layout (bytes)
#define XB_OFF 0
#define TB_OFF ((size_t)N_TOK * IN_F * 2)                      // 2 MiB of bf16 x
#define PO_OFF (TB_OFF + (size_t)LKC * N_TOK * RANK * 4)       // + 64 KiB t-partials
// pO: KSPLIT * 128 * 8192 f32 = 64 MiB

__device__ __forceinline__ unsigned short bf16r(float f) {
    uint32_t u = __float_as_uint(f);
    return (unsigned short)((u + 0x7FFFu + ((u >> 16) & 1u)) >> 16);
}

// ---------------- kernel A: x fp32 -> bf16 ----------------
__global__ __launch_bounds__(256) void cvt_x(const float* __restrict__ x,
                                             unsigned short* __restrict__ xb) {
    size_t i = ((size_t)blockIdx.x * 256 + threadIdx.x) * 8;
    float4 a = *(const float4*)(x + i);
    float4 b = *(const float4*)(x + i + 4);
    ushort8 o;
    o[0] = bf16r(a.x); o[1] = bf16r(a.y); o[2] = bf16r(a.z); o[3] = bf16r(a.w);
    o[4] = bf16r(b.x); o[5] = bf16r(b.y); o[6] = bf16r(b.z); o[7] = bf16r(b.w);
    *(ushort8*)(xb + i) = o;
}

// ---------------- kernel B: t-partials = x @ lora_B^T, coalesced ----------------
// grid = 128 m * 4 kc = 512 blocks. Thread owns 8 consecutive cols; computes
// its 8-col dot contribution for ALL 32 ranks (coalesced B reads), then LDS
// tree reduce: 256 threads -> 8 groups -> 32 rank outputs.
__global__ __launch_bounds__(256) void lora_t(const float* __restrict__ x,
                                              const float* __restrict__ lb,
                                              float* __restrict__ tB) {
    __shared__ float ts[256][33];   // [thread][rank], pad 33 -> conflict-free cols
    __shared__ float ps[8][32];
    const int m = blockIdx.x >> 2, kc = blockIdx.x & 3;
    const int tid = threadIdx.x;
    const int c0 = kc * 2048 + tid * 8;
    float4 xv0 = *(const float4*)(x + (size_t)m * IN_F + c0);
    float4 xv1 = *(const float4*)(x + (size_t)m * IN_F + c0 + 4);
#pragma unroll
    for (int r = 0; r < RANK; ++r) {
        const float4* bp = (const float4*)(lb + (size_t)r * IN_F + c0);
        float4 b0 = bp[0], b1 = bp[1];
        float s = xv0.x * b0.x + xv0.y * b0.y + xv0.z * b0.z + xv0.w * b0.w +
                  xv1.x * b1.x + xv1.y * b1.y + xv1.z * b1.z + xv1.w * b1.w;
        ts[tid][r] = s;
    }
    __syncthreads();
    {
        int g = tid >> 5, r = tid & 31;
        float s = 0.f;
        for (int j = 0; j < 32; ++j) s += ts[g * 32 + j][r];
        ps[g][r] = s;
    }
    __syncthreads();
    if (tid < 32) {
        float s = 0.f;
#pragma unroll
        for (int g = 0; g < 8; ++g) s += ps[g][tid];
        tB[(kc * N_TOK + m) * RANK + tid] = s;
    }
}

// ---------------- decode: 32-bit packed (16 ternary codes) -> 8 dwords of bf16 pairs ----------------
__device__ __forceinline__ void decode16(uint32_t p, uint32_t d[8]) {
    const uint32_t HI = 0x403F00BFu;  // high-byte table (sel>=4 -> src0)
    const uint32_t LO = 0x00800080u;  // low-byte table  (sel<4  -> src1)
#pragma unroll
    for (int j = 0; j < 8; ++j) {
        uint32_t c0 = (p >> (4 * j)) & 3u;
        uint32_t c1 = (p >> (4 * j + 2)) & 3u;
        uint32_t t = c0 | (c1 << 16);
        uint32_t sel = (t | (t << 8)) + 0x04000400u;
        d[j] = __builtin_amdgcn_perm(HI, LO, sel);
    }
}

__device__ __forceinline__ int swz(int row, int col) { return col ^ ((row & 7) << 3); }

// ---------------- kernel C: main ternary GEMM ----------------
// weight_packed arrives as int32 (harness widens uint8 inputs).
// grid = 64 n-tiles * KSPLIT(16) = 1024 blocks, 256 threads (4 waves, 2x2 of 64x64)
__global__ __launch_bounds__(256) void ternary_gemm(const unsigned short* __restrict__ xb,
                                                    const int* __restrict__ wp,
                                                    float* __restrict__ pO) {
    __shared__ unsigned short xs[128][64];  // XOR-swizzled, no pad
    __shared__ unsigned short ww[128][64];
    const int tid = threadIdx.x;
    const int nb = blockIdx.x >> 4;
    const int ks = blockIdx.x & 15;
    const int n0 = nb * 128;
    const int k0 = ks * KB;
    const int lane = tid & 63;
    const int wid = tid >> 6;
    const int wr = wid >> 1, wc = wid & 1;

    const int srow = tid >> 2;
    const int xcol = (tid & 3) * 16;
    const unsigned short* xg0 = xb + (size_t)srow * IN_F + k0 + xcol;
    const unsigned short* xg1 = xg0 + (size_t)64 * IN_F;
    const int pcol = (tid & 3) * 4;
    const int* pg0 = wp + (size_t)(n0 + srow) * (IN_F / 4) + (k0 >> 2) + pcol;
    const int* pg1 = pg0 + (size_t)64 * (IN_F / 4);

    f32x4 acc[4][4];
#pragma unroll
    for (int i = 0; i < 4; ++i)
#pragma unroll
        for (int j = 0; j < 4; ++j) acc[i][j] = (f32x4){0.f, 0.f, 0.f, 0.f};

    const int arow = lane & 15;
    const int kgrp = (lane >> 4) * 8;

    // swizzled write columns (constant per thread)
    const int wc0 = swz(srow, xcol), wc1 = swz(srow, xcol + 8);

    // prime: load step 0
    uint4 cx0a = *(const uint4*)(xg0);
    uint4 cx0b = *(const uint4*)(xg0 + 8);
    uint4 cx1a = *(const uint4*)(xg1);
    uint4 cx1b = *(const uint4*)(xg1 + 8);
    int4 cp0 = *(const int4*)(pg0);
    int4 cp1 = *(const int4*)(pg1);

    for (int s = 0; s < NSTEP; ++s) {
        uint4 nx0a, nx0b, nx1a, nx1b;
        int4 np0, np1;
        if (s + 1 < NSTEP) {  // prefetch next step; latency hides under barriers+MFMA
            const unsigned short* a0 = xg0 + (s + 1) * BK;
            const unsigned short* a1 = xg1 + (s + 1) * BK;
            nx0a = *(const uint4*)(a0);
            nx0b = *(const uint4*)(a0 + 8);
            nx1a = *(const uint4*)(a1);
            nx1b = *(const uint4*)(a1 + 8);
            np0 = *(const int4*)(pg0 + (s + 1) * (BK / 4));
            np1 = *(const int4*)(pg1 + (s + 1) * (BK / 4));
        }
        // decode current (int values are 0..255 -> pack low bytes)
        uint32_t p0 = (uint32_t)cp0.x | ((uint32_t)cp0.y << 8) |
                      ((uint32_t)cp0.z << 16) | ((uint32_t)cp0.w << 24);
        uint32_t p1 = (uint32_t)cp1.x | ((uint32_t)cp1.y << 8) |
                      ((uint32_t)cp1.z << 16) | ((uint32_t)cp1.w << 24);
        uint32_t d0[8], d1[8];
        decode16(p0, d0);
        decode16(p1, d1);
        __syncthreads();  // previous tile fully consumed
        *(uint4*)&xs[srow][wc0] = cx0a;
        *(uint4*)&xs[srow][wc1] = cx0b;
        *(uint4*)&xs[srow + 64][wc0] = cx1a;
        *(uint4*)&xs[srow + 64][wc1] = cx1b;
        *(uint4*)&ww[srow][wc0] = make_uint4(d0[0], d0[1], d0[2], d0[3]);
        *(uint4*)&ww[srow][wc1] = make_uint4(d0[4], d0[5], d0[6], d0[7]);
        *(uint4*)&ww[srow + 64][wc0] = make_uint4(d1[0], d1[1], d1[2], d1[3]);
        *(uint4*)&ww[srow + 64][wc1] = make_uint4(d1[4], d1[5], d1[6], d1[7]);
        __syncthreads();
#pragma unroll
        for (int kk = 0; kk < 2; ++kk) {
            const int kcol = kk * 32 + kgrp;
            bf16x8 af[4], bfr[4];
#pragma unroll
            for (int ar = 0; ar < 4; ++ar) {
                int row = wr * 64 + ar * 16 + arow;
                af[ar] = *(const bf16x8*)&xs[row][swz(row, kcol)];
            }
#pragma unroll
            for (int br = 0; br < 4; ++br) {
                int row = wc * 64 + br * 16 + arow;
                bfr[br] = *(const bf16x8*)&ww[row][swz(row, kcol)];
            }
#pragma unroll
            for (int ar = 0; ar < 4; ++ar)
#pragma unroll
                for (int br = 0; br < 4; ++br)
                    acc[ar][br] = __builtin_amdgcn_mfma_f32_16x16x32_bf16(
                        af[ar], bfr[br], acc[ar][br], 0, 0, 0);
        }
        if (s + 1 < NSTEP) {
            cx0a = nx0a; cx0b = nx0b; cx1a = nx1a; cx1b = nx1b;
            cp0 = np0; cp1 = np1;
        }
    }

    // epilogue: raw partial store
    float* po = pO + ((size_t)ks << 20);
    const int mrow = (lane >> 4) * 4;
#pragma unroll
    for (int ar = 0; ar < 4; ++ar) {
#pragma unroll
        for (int br = 0; br < 4; ++br) {
            int m = wr * 64 + ar * 16 + mrow;
            int n = n0 + wc * 64 + br * 16 + arow;
            float* pp = po + (size_t)m * OUT_F + n;
#pragma unroll
            for (int j = 0; j < 4; ++j) pp[(size_t)j * OUT_F] = acc[ar][br][j];
        }
    }
}

// ---------------- kernel D: reduce partials + scale + lora + bias ----------------
__global__ __launch_bounds__(256) void reduce_out(const float* __restrict__ pO,
                                                  const float* __restrict__ tB,
                                                  const float* __restrict__ scale,
                                                  const float* __restrict__ lora_A,
                                                  const float* __restrict__ bias,
                                                  float* __restrict__ out) {
    __shared__ float ts[8][RANK];
    int nb = blockIdx.x & 31, mg = blockIdx.x >> 5;
    int tid = threadIdx.x;
    int m0 = mg * 8;
    {
        int i = tid >> 5, r = tid & 31;
        float s = 0.f;
#pragma unroll
        for (int c = 0; c < LKC; ++c) s += tB[(c * N_TOK + m0 + i) * RANK + r];
        ts[i][r] = s;
    }
    __syncthreads();
    int n = nb * 256 + tid;
    float sc = scale[n], bs = bias[n];
    float4 a4[8];
    const float4* ap = (const float4*)(lora_A + (size_t)n * RANK);
#pragma unroll
    for (int q = 0; q < 8; ++q) a4[q] = ap[q];
#pragma unroll
    for (int i = 0; i < 8; ++i) {
        int m = m0 + i;
        const float* pp = pO + (size_t)m * OUT_F + n;
        float s = 0.f;
#pragma unroll
        for (int c = 0; c < KSPLIT; ++c) s += pp[(size_t)c << 20];
        float l = 0.f;
#pragma unroll
        for (int q = 0; q < 8; ++q) {
            float4 tv = *(const float4*)&ts[i][q * 4];
            l = fmaf(tv.x, a4[q].x, l);
            l = fmaf(tv.y, a4[q].y, l);
            l = fmaf(tv.z, a4[q].z, l);
            l = fmaf(tv.w, a4[q].w, l);
        }
        out[(size_t)m * OUT_F + n] = fmaf(s, sc, l + bs);
    }
}

extern "C" void kernel_launch(void* const* d_in, const int* in_sizes, int n_in,
                              void* d_out, int out_size, void* d_ws, size_t ws_size,
                              hipStream_t stream) {
    const float* x      = (const float*)d_in[0];
    const int*   wp     = (const int*)d_in[1];   // uint8 input -> int32 on device
    const float* scale  = (const float*)d_in[2];
    const float* lora_A = (const float*)d_in[3];
    const float* lora_B = (const float*)d_in[4];
    const float* bias   = (const float*)d_in[5];
    float* out = (float*)d_out;

    char* ws = (char*)d_ws;
    unsigned short* xb = (unsigned short*)(ws + XB_OFF);
    float* tB = (float*)(ws + TB_OFF);
    float* pO = (float*)(ws + PO_OFF);

    cvt_x<<<(N_TOK * IN_F) / (256 * 8), 256, 0, stream>>>(x, xb);
    lora_t<<<N_TOK * LKC, 256, 0, stream>>>(x, lora_B, tB);
    ternary_gemm<<<(OUT_F / 128) * KSPLIT, 256, 0, stream>>>(xb, wp, pO);
    reduce_out<<<(OUT_F / 256) * (N_TOK / 8), 256, 0, stream>>>(pO, tB, scale, lora_A, bias, out);
}

// Round 5
// 55.056 us; speedup vs baseline: 1.5130x; 1.1176x over previous
//
#include <hip/hip_runtime.h>
#include <hip/hip_bf16.h>
#include <stdint.h>

typedef float f32x4 __attribute__((ext_vector_type(4)));
typedef __bf16 bf16x8 __attribute__((ext_vector_type(8)));
typedef unsigned short ushort8 __attribute__((ext_vector_type(8)));

#define N_TOK 128
#define OUT_F 8192
#define IN_F  8192
#define RANK  32

#define KSPLIT 16               // main-gemm k-split
#define KB    (IN_F / KSPLIT)   // 512 per block
#define BK    64
#define NSTEP (KB / BK)         // 8
#define WSTRIDE 16              // ints per step per W row (BK/4)
#define LKC   4                 // lora-t k-chunks

// workspace layout (bytes)
#define XB_OFF 0
#define TB_OFF ((size_t)N_TOK * IN_F * 2)                      // 2 MiB of bf16 x
#define PO_OFF (TB_OFF + (size_t)LKC * N_TOK * RANK * 4)       // + 64 KiB t-partials
// pO: KSPLIT * 128 * 8192 bf16 = 32 MiB

__device__ __forceinline__ unsigned short bf16r(float f) {
    uint32_t u = __float_as_uint(f);
    return (unsigned short)((u + 0x7FFFu + ((u >> 16) & 1u)) >> 16);
}

// ---------------- kernel A: x fp32 -> bf16 ----------------
__global__ __launch_bounds__(256) void cvt_x(const float* __restrict__ x,
                                             unsigned short* __restrict__ xb) {
    size_t i = ((size_t)blockIdx.x * 256 + threadIdx.x) * 8;
    float4 a = *(const float4*)(x + i);
    float4 b = *(const float4*)(x + i + 4);
    ushort8 o;
    o[0] = bf16r(a.x); o[1] = bf16r(a.y); o[2] = bf16r(a.z); o[3] = bf16r(a.w);
    o[4] = bf16r(b.x); o[5] = bf16r(b.y); o[6] = bf16r(b.z); o[7] = bf16r(b.w);
    *(ushort8*)(xb + i) = o;
}

// ---------------- kernel B: t-partials = x @ lora_B^T, coalesced ----------------
__global__ __launch_bounds__(256) void lora_t(const float* __restrict__ x,
                                              const float* __restrict__ lb,
                                              float* __restrict__ tB) {
    __shared__ float ts[256][33];
    __shared__ float ps[8][32];
    const int m = blockIdx.x >> 2, kc = blockIdx.x & 3;
    const int tid = threadIdx.x;
    const int c0 = kc * 2048 + tid * 8;
    float4 xv0 = *(const float4*)(x + (size_t)m * IN_F + c0);
    float4 xv1 = *(const float4*)(x + (size_t)m * IN_F + c0 + 4);
#pragma unroll
    for (int r = 0; r < RANK; ++r) {
        const float4* bp = (const float4*)(lb + (size_t)r * IN_F + c0);
        float4 b0 = bp[0], b1 = bp[1];
        float s = xv0.x * b0.x + xv0.y * b0.y + xv0.z * b0.z + xv0.w * b0.w +
                  xv1.x * b1.x + xv1.y * b1.y + xv1.z * b1.z + xv1.w * b1.w;
        ts[tid][r] = s;
    }
    __syncthreads();
    {
        int g = tid >> 5, r = tid & 31;
        float s = 0.f;
        for (int j = 0; j < 32; ++j) s += ts[g * 32 + j][r];
        ps[g][r] = s;
    }
    __syncthreads();
    if (tid < 32) {
        float s = 0.f;
#pragma unroll
        for (int g = 0; g < 8; ++g) s += ps[g][tid];
        tB[(kc * N_TOK + m) * RANK + tid] = s;
    }
}

// ---------------- decode: 16 ternary codes (from 4 widened ints) -> 8 dwords of bf16 pairs ----------------
__device__ __forceinline__ void decodeW(int4 v, uint32_t d[8]) {
    uint32_t p = (uint32_t)v.x | ((uint32_t)v.y << 8) |
                 ((uint32_t)v.z << 16) | ((uint32_t)v.w << 24);
    const uint32_t HI = 0x403F00BFu;  // high-byte LUT (sel>=4 -> src0)
    const uint32_t LO = 0x00800080u;  // low-byte LUT  (sel<4  -> src1)
#pragma unroll
    for (int j = 0; j < 8; ++j) {
        uint32_t c0 = (p >> (4 * j)) & 3u;
        uint32_t c1 = (p >> (4 * j + 2)) & 3u;
        uint32_t t = c0 | (c1 << 16);
        uint32_t sel = (t | (t << 8)) + 0x04000400u;
        d[j] = __builtin_amdgcn_perm(HI, LO, sel);
    }
}

__device__ __forceinline__ int swz(int row, int col) { return col ^ ((row & 7) << 3); }

// ---------------- kernel C: main ternary GEMM, decode-ahead pipeline ----------------
// grid = 64 n-tiles * KSPLIT(16) = 1024 blocks, 256 threads (4 waves, 2x2 of 64x64)
__global__ __launch_bounds__(256) void ternary_gemm(const unsigned short* __restrict__ xb,
                                                    const int* __restrict__ wp,
                                                    unsigned short* __restrict__ pO) {
    __shared__ unsigned short xs[128][64];
    __shared__ unsigned short ww[128][64];
    const int tid = threadIdx.x;
    const int nb = blockIdx.x >> 4;
    const int ks = blockIdx.x & 15;
    const int n0 = nb * 128;
    const int k0 = ks * KB;
    const int lane = tid & 63;
    const int wid = tid >> 6;
    const int wr = wid >> 1, wc = wid & 1;

    const int srow = tid >> 2;
    const int xcol = (tid & 3) * 16;
    const unsigned short* xg0 = xb + (size_t)srow * IN_F + k0 + xcol;
    const unsigned short* xg1 = xg0 + (size_t)64 * IN_F;
    const int pcol = (tid & 3) * 4;
    const int* pg0 = wp + (size_t)(n0 + srow) * (IN_F / 4) + (k0 >> 2) + pcol;
    const int* pg1 = pg0 + (size_t)64 * (IN_F / 4);

    f32x4 acc[4][4];
#pragma unroll
    for (int i = 0; i < 4; ++i)
#pragma unroll
        for (int j = 0; j < 4; ++j) acc[i][j] = (f32x4){0.f, 0.f, 0.f, 0.f};

    const int arow = lane & 15;
    const int kgrp = (lane >> 4) * 8;
    const int wc0 = swz(srow, xcol), wc1 = swz(srow, xcol + 8);

    // ---- prologue: x(0), W(0) decoded, W(1) in flight ----
    uint4 xw0a = *(const uint4*)(xg0);
    uint4 xw0b = *(const uint4*)(xg0 + 8);
    uint4 xw1a = *(const uint4*)(xg1);
    uint4 xw1b = *(const uint4*)(xg1 + 8);
    uint32_t d0[8], d1[8];
    int4 w0A, w1A, w0B, w1B;
    {
        int4 t0 = *(const int4*)(pg0);
        int4 t1 = *(const int4*)(pg1);
        w0A = *(const int4*)(pg0 + WSTRIDE);
        w1A = *(const int4*)(pg1 + WSTRIDE);
        decodeW(t0, d0);
        decodeW(t1, d1);
    }

#pragma unroll
    for (int s = 0; s < NSTEP; ++s) {
        __syncthreads();  // previous tile fully consumed
        // stage step s (x regs + pre-decoded W regs)
        *(uint4*)&xs[srow][wc0] = xw0a;
        *(uint4*)&xs[srow][wc1] = xw0b;
        *(uint4*)&xs[srow + 64][wc0] = xw1a;
        *(uint4*)&xs[srow + 64][wc1] = xw1b;
        *(uint4*)&ww[srow][wc0] = make_uint4(d0[0], d0[1], d0[2], d0[3]);
        *(uint4*)&ww[srow][wc1] = make_uint4(d0[4], d0[5], d0[6], d0[7]);
        *(uint4*)&ww[srow + 64][wc0] = make_uint4(d1[0], d1[1], d1[2], d1[3]);
        *(uint4*)&ww[srow + 64][wc1] = make_uint4(d1[4], d1[5], d1[6], d1[7]);
        // issue x(s+1) (1-deep, L2-resident source)
        if (s + 1 < NSTEP) {
            const unsigned short* a0 = xg0 + (s + 1) * BK;
            const unsigned short* a1 = xg1 + (s + 1) * BK;
            xw0a = *(const uint4*)(a0);
            xw0b = *(const uint4*)(a0 + 8);
            xw1a = *(const uint4*)(a1);
            xw1b = *(const uint4*)(a1 + 8);
        }
        // issue W(s+2) into the free parity slot (2-deep, HBM/L3 source)
        if ((s & 1) == 0) {
            if (s + 2 < NSTEP) {
                w0B = *(const int4*)(pg0 + (s + 2) * WSTRIDE);
                w1B = *(const int4*)(pg1 + (s + 2) * WSTRIDE);
            }
        } else {
            if (s + 2 < NSTEP) {
                w0A = *(const int4*)(pg0 + (s + 2) * WSTRIDE);
                w1A = *(const int4*)(pg1 + (s + 2) * WSTRIDE);
            }
        }
        __syncthreads();
        // decode W(s+1) — VALU work the scheduler interleaves with MFMA below
        if (s + 1 < NSTEP) {
            if ((s & 1) == 0) { decodeW(w0A, d0); decodeW(w1A, d1); }
            else              { decodeW(w0B, d0); decodeW(w1B, d1); }
        }
        // MFMA step s
#pragma unroll
        for (int kk = 0; kk < 2; ++kk) {
            const int kcol = kk * 32 + kgrp;
            bf16x8 af[4], bfr[4];
#pragma unroll
            for (int ar = 0; ar < 4; ++ar) {
                int row = wr * 64 + ar * 16 + arow;
                af[ar] = *(const bf16x8*)&xs[row][swz(row, kcol)];
            }
#pragma unroll
            for (int br = 0; br < 4; ++br) {
                int row = wc * 64 + br * 16 + arow;
                bfr[br] = *(const bf16x8*)&ww[row][swz(row, kcol)];
            }
#pragma unroll
            for (int ar = 0; ar < 4; ++ar)
#pragma unroll
                for (int br = 0; br < 4; ++br)
                    acc[ar][br] = __builtin_amdgcn_mfma_f32_16x16x32_bf16(
                        af[ar], bfr[br], acc[ar][br], 0, 0, 0);
        }
    }

    // epilogue: bf16 partial store
    unsigned short* po = pO + ((size_t)ks << 20);
    const int mrow = (lane >> 4) * 4;
#pragma unroll
    for (int ar = 0; ar < 4; ++ar) {
#pragma unroll
        for (int br = 0; br < 4; ++br) {
            int m = wr * 64 + ar * 16 + mrow;
            int n = n0 + wc * 64 + br * 16 + arow;
            unsigned short* pp = po + (size_t)m * OUT_F + n;
#pragma unroll
            for (int j = 0; j < 4; ++j) pp[(size_t)j * OUT_F] = bf16r(acc[ar][br][j]);
        }
    }
}

// ---------------- kernel D: reduce bf16 partials + scale + lora + bias ----------------
// grid = 16 nb * 32 mg = 512 blocks; thread: 2 consecutive n, 4 m's
__global__ __launch_bounds__(256) void reduce_out(const unsigned short* __restrict__ pO,
                                                  const float* __restrict__ tB,
                                                  const float* __restrict__ scale,
                                                  const float* __restrict__ lora_A,
                                                  const float* __restrict__ bias,
                                                  float* __restrict__ out) {
    __shared__ float ts[4][RANK];
    int nb = blockIdx.x & 15, mg = blockIdx.x >> 4;
    int tid = threadIdx.x;
    int m0 = mg * 4;
    if (tid < 128) {
        int i = tid >> 5, r = tid & 31;
        float s = 0.f;
#pragma unroll
        for (int c = 0; c < LKC; ++c) s += tB[(c * N_TOK + m0 + i) * RANK + r];
        ts[i][r] = s;
    }
    __syncthreads();
    int n = nb * 512 + tid * 2;
    float sc0 = scale[n], sc1 = scale[n + 1];
    float bs0 = bias[n], bs1 = bias[n + 1];
    float4 a0[8], a1[8];
    const float4* ap0 = (const float4*)(lora_A + (size_t)n * RANK);
    const float4* ap1 = (const float4*)(lora_A + (size_t)(n + 1) * RANK);
#pragma unroll
    for (int q = 0; q < 8; ++q) { a0[q] = ap0[q]; a1[q] = ap1[q]; }
#pragma unroll
    for (int i = 0; i < 4; ++i) {
        int m = m0 + i;
        const unsigned short* pp = pO + (size_t)m * OUT_F + n;
        float s0 = 0.f, s1 = 0.f;
#pragma unroll
        for (int c = 0; c < KSPLIT; ++c) {
            uint32_t u = *(const uint32_t*)(pp + ((size_t)c << 20));
            s0 += __uint_as_float(u << 16);
            s1 += __uint_as_float(u & 0xFFFF0000u);
        }
        float l0 = 0.f, l1 = 0.f;
#pragma unroll
        for (int q = 0; q < 8; ++q) {
            float4 tv = *(const float4*)&ts[i][q * 4];
            l0 = fmaf(tv.x, a0[q].x, l0); l0 = fmaf(tv.y, a0[q].y, l0);
            l0 = fmaf(tv.z, a0[q].z, l0); l0 = fmaf(tv.w, a0[q].w, l0);
            l1 = fmaf(tv.x, a1[q].x, l1); l1 = fmaf(tv.y, a1[q].y, l1);
            l1 = fmaf(tv.z, a1[q].z, l1); l1 = fmaf(tv.w, a1[q].w, l1);
        }
        out[(size_t)m * OUT_F + n]     = fmaf(s0, sc0, l0 + bs0);
        out[(size_t)m * OUT_F + n + 1] = fmaf(s1, sc1, l1 + bs1);
    }
}

extern "C" void kernel_launch(void* const* d_in, const int* in_sizes, int n_in,
                              void* d_out, int out_size, void* d_ws, size_t ws_size,
                              hipStream_t stream) {
    const float* x      = (const float*)d_in[0];
    const int*   wp     = (const int*)d_in[1];   // uint8 input -> int32 on device
    const float* scale  = (const float*)d_in[2];
    const float* lora_A = (const float*)d_in[3];
    const float* lora_B = (const float*)d_in[4];
    const float* bias   = (const float*)d_in[5];
    float* out = (float*)d_out;

    char* ws = (char*)d_ws;
    unsigned short* xb = (unsigned short*)(ws + XB_OFF);
    float* tB = (float*)(ws + TB_OFF);
    unsigned short* pO = (unsigned short*)(ws + PO_OFF);

    cvt_x<<<(N_TOK * IN_F) / (256 * 8), 256, 0, stream>>>(x, xb);
    lora_t<<<N_TOK * LKC, 256, 0, stream>>>(x, lora_B, tB);
    ternary_gemm<<<(OUT_F / 128) * KSPLIT, 256, 0, stream>>>(xb, wp, pO);
    reduce_out<<<16 * 32, 256, 0, stream>>>(pO, tB, scale, lora_A, bias, out);
}

// Round 6
// 54.420 us; speedup vs baseline: 1.5307x; 1.0117x over previous
//
#include <hip/hip_runtime.h>
#include <hip/hip_bf16.h>
#include <stdint.h>

typedef float f32x4 __attribute__((ext_vector_type(4)));
typedef __bf16 bf16x8 __attribute__((ext_vector_type(8)));
typedef unsigned short ushort8 __attribute__((ext_vector_type(8)));

typedef const __attribute__((address_space(1))) uint32_t gu32;
typedef __attribute__((address_space(3))) uint32_t lu32;

#define N_TOK 128
#define OUT_F 8192
#define IN_F  8192
#define RANK  32

#define KSPLIT 8                // main-gemm k-split
#define KB    (IN_F / KSPLIT)   // 1024 per block
#define BK    64
#define NSTEP (KB / BK)         // 16
#define WSTRIDE 16              // ints per step per W row (BK/4)
#define LKC   4                 // lora-t k-chunks

// workspace layout (bytes)
#define XB_OFF 0
#define TB_OFF ((size_t)N_TOK * IN_F * 2)                      // 2 MiB tile-ordered bf16 x
#define PO_OFF (TB_OFF + (size_t)LKC * N_TOK * RANK * 4)       // + 64 KiB t-partials
// pO: KSPLIT * 128 * 8192 bf16 = 16 MiB

__device__ __forceinline__ unsigned short bf16r(float f) {
    uint32_t u = __float_as_uint(f);
    return (unsigned short)((u + 0x7FFFu + ((u >> 16) & 1u)) >> 16);
}

__device__ __forceinline__ int swz(int row, int col) { return col ^ ((row & 7) << 3); }

// ---------------- kernel A: x fp32 -> bf16, GEMM-tile order, pre-swizzled ----------------
// xt layout: chunk index f = ((sblk*128 + r)*8 + c8), 8 bf16 per chunk, holding
// X(r, sblk*64 + ((c8 ^ (r&7))*8 + e).  Then a linear global_load_lds of 16 KiB
// produces exactly the XOR-swizzled LDS image the MFMA readers expect.
__global__ __launch_bounds__(256) void cvt_x(const float* __restrict__ x,
                                             unsigned short* __restrict__ xt) {
    size_t f = (size_t)blockIdx.x * 256 + threadIdx.x;  // 0..131071
    int c8 = (int)(f & 7);
    int r = (int)((f >> 3) & 127);
    int sblk = (int)(f >> 10);  // 0..127
    int k = sblk * 64 + ((c8 ^ (r & 7)) << 3);
    const float4* sp = (const float4*)(x + (size_t)r * IN_F + k);
    float4 a = sp[0], b = sp[1];
    ushort8 o;
    o[0] = bf16r(a.x); o[1] = bf16r(a.y); o[2] = bf16r(a.z); o[3] = bf16r(a.w);
    o[4] = bf16r(b.x); o[5] = bf16r(b.y); o[6] = bf16r(b.z); o[7] = bf16r(b.w);
    *(ushort8*)(xt + f * 8) = o;
}

// ---------------- kernel B: t-partials = x @ lora_B^T, coalesced ----------------
__global__ __launch_bounds__(256) void lora_t(const float* __restrict__ x,
                                              const float* __restrict__ lb,
                                              float* __restrict__ tB) {
    __shared__ float ts[256][33];
    __shared__ float ps[8][32];
    const int m = blockIdx.x >> 2, kc = blockIdx.x & 3;
    const int tid = threadIdx.x;
    const int c0 = kc * 2048 + tid * 8;
    float4 xv0 = *(const float4*)(x + (size_t)m * IN_F + c0);
    float4 xv1 = *(const float4*)(x + (size_t)m * IN_F + c0 + 4);
#pragma unroll
    for (int r = 0; r < RANK; ++r) {
        const float4* bp = (const float4*)(lb + (size_t)r * IN_F + c0);
        float4 b0 = bp[0], b1 = bp[1];
        float s = xv0.x * b0.x + xv0.y * b0.y + xv0.z * b0.z + xv0.w * b0.w +
                  xv1.x * b1.x + xv1.y * b1.y + xv1.z * b1.z + xv1.w * b1.w;
        ts[tid][r] = s;
    }
    __syncthreads();
    {
        int g = tid >> 5, r = tid & 31;
        float s = 0.f;
        for (int j = 0; j < 32; ++j) s += ts[g * 32 + j][r];
        ps[g][r] = s;
    }
    __syncthreads();
    if (tid < 32) {
        float s = 0.f;
#pragma unroll
        for (int g = 0; g < 8; ++g) s += ps[g][tid];
        tB[(kc * N_TOK + m) * RANK + tid] = s;
    }
}

// ---------------- decode: 16 ternary codes (4 widened ints) -> 8 dwords of bf16 pairs ----------------
__device__ __forceinline__ void decodeW(int4 v, uint32_t d[8]) {
    uint32_t p = (uint32_t)v.x | ((uint32_t)v.y << 8) |
                 ((uint32_t)v.z << 16) | ((uint32_t)v.w << 24);
    const uint32_t HI = 0x403F00BFu;
    const uint32_t LO = 0x00800080u;
#pragma unroll
    for (int j = 0; j < 8; ++j) {
        uint32_t c0 = (p >> (4 * j)) & 3u;
        uint32_t c1 = (p >> (4 * j + 2)) & 3u;
        uint32_t t = c0 | (c1 << 16);
        uint32_t sel = (t | (t << 8)) + 0x04000400u;
        d[j] = __builtin_amdgcn_perm(HI, LO, sel);
    }
}

// ---------------- kernel C: ternary GEMM, LDS double-buffer + x-DMA, 1 barrier/step ----------------
// grid = 64 n-tiles * KSPLIT(8) = 512 blocks, 256 threads (4 waves, 2x2 of 64x64)
__global__ __launch_bounds__(256) void ternary_gemm(const unsigned short* __restrict__ xt,
                                                    const int* __restrict__ wp,
                                                    unsigned short* __restrict__ pO) {
    __shared__ unsigned short xs[2][128][64];  // 2 x 16 KiB, DMA'd linear (pre-swizzled src)
    __shared__ unsigned short ww[2][128][64];  // 2 x 16 KiB, decoded + XOR-swizzled writes
    const int tid = threadIdx.x;
    const int nb = blockIdx.x >> 3;
    const int ks = blockIdx.x & 7;
    const int n0 = nb * 128;
    const int lane = tid & 63;
    const int wid = tid >> 6;
    const int wr = wid >> 1, wc = wid & 1;

    const int srow = tid >> 2;
    const int xcol = (tid & 3) * 16;
    const int* pg0 = wp + (size_t)(n0 + srow) * (IN_F / 4) + ks * (KB / 4) + (tid & 3) * 4;
    const int* pg1 = pg0 + (size_t)64 * (IN_F / 4);

    // DMA source: per step s, 16 KiB at xt + (ks*NSTEP+s)*8192; wave wid covers
    // rows j*32 + wid*8 .. +8 per call j; per-lane address is linear (+lane*16B).
    const unsigned short* xsrc = xt + ((size_t)(ks * NSTEP) * 128 + wid * 8) * 64 + lane * 8;

    f32x4 acc[4][4];
#pragma unroll
    for (int i = 0; i < 4; ++i)
#pragma unroll
        for (int j = 0; j < 4; ++j) acc[i][j] = (f32x4){0.f, 0.f, 0.f, 0.f};

    const int arow = lane & 15;
    const int kgrp = (lane >> 4) * 8;
    const int wc0 = swz(srow, xcol), wc1 = swz(srow, xcol + 8);

    // ---------- prologue: Wp(0) decode -> ww[0]; DMA x(0) -> xs[0]; Wp(1) in regs ----------
    int4 wA0 = *(const int4*)(pg0);
    int4 wA1 = *(const int4*)(pg1);
#pragma unroll
    for (int j = 0; j < 4; ++j)
        __builtin_amdgcn_global_load_lds(
            (gu32*)(xsrc + j * 2048),
            (lu32*)((char*)(&xs[0][0][0]) + wid * 1024 + j * 4096), 16, 0, 0);
    int4 wB0 = *(const int4*)(pg0 + WSTRIDE);
    int4 wB1 = *(const int4*)(pg1 + WSTRIDE);
    {
        uint32_t d0[8], d1[8];
        decodeW(wA0, d0);
        decodeW(wA1, d1);
        *(uint4*)&ww[0][srow][wc0]      = make_uint4(d0[0], d0[1], d0[2], d0[3]);
        *(uint4*)&ww[0][srow][wc1]      = make_uint4(d0[4], d0[5], d0[6], d0[7]);
        *(uint4*)&ww[0][srow + 64][wc0] = make_uint4(d1[0], d1[1], d1[2], d1[3]);
        *(uint4*)&ww[0][srow + 64][wc1] = make_uint4(d1[4], d1[5], d1[6], d1[7]);
    }
    __syncthreads();

#pragma unroll
    for (int s = 0; s < NSTEP; ++s) {
        const int cur = s & 1, nxt = cur ^ 1;
        // issue Wp(s+2) into the reg set freed by this step's decode
        if (s + 2 < NSTEP) {
            if ((s & 1) == 0) {
                wA0 = *(const int4*)(pg0 + (s + 2) * WSTRIDE);
                wA1 = *(const int4*)(pg1 + (s + 2) * WSTRIDE);
            } else {
                wB0 = *(const int4*)(pg0 + (s + 2) * WSTRIDE);
                wB1 = *(const int4*)(pg1 + (s + 2) * WSTRIDE);
            }
        }
        if (s + 1 < NSTEP) {
            // DMA x(s+1) -> xs[nxt]
#pragma unroll
            for (int j = 0; j < 4; ++j)
                __builtin_amdgcn_global_load_lds(
                    (gu32*)(xsrc + (size_t)(s + 1) * (128 * 64) + j * 2048),
                    (lu32*)((char*)(&xs[nxt][0][0]) + wid * 1024 + j * 4096), 16, 0, 0);
            // decode Wp(s+1) -> ww[nxt]
            uint32_t d0[8], d1[8];
            if ((s & 1) == 0) { decodeW(wB0, d0); decodeW(wB1, d1); }
            else              { decodeW(wA0, d0); decodeW(wA1, d1); }
            *(uint4*)&ww[nxt][srow][wc0]      = make_uint4(d0[0], d0[1], d0[2], d0[3]);
            *(uint4*)&ww[nxt][srow][wc1]      = make_uint4(d0[4], d0[5], d0[6], d0[7]);
            *(uint4*)&ww[nxt][srow + 64][wc0] = make_uint4(d1[0], d1[1], d1[2], d1[3]);
            *(uint4*)&ww[nxt][srow + 64][wc1] = make_uint4(d1[4], d1[5], d1[6], d1[7]);
        }
        // MFMA on cur buffers (drain + barrier comes after -> loads get MFMA cover)
#pragma unroll
        for (int kk = 0; kk < 2; ++kk) {
            const int kcol = kk * 32 + kgrp;
            bf16x8 af[4], bfr[4];
#pragma unroll
            for (int ar = 0; ar < 4; ++ar) {
                int row = wr * 64 + ar * 16 + arow;
                af[ar] = *(const bf16x8*)&xs[cur][row][swz(row, kcol)];
            }
#pragma unroll
            for (int br = 0; br < 4; ++br) {
                int row = wc * 64 + br * 16 + arow;
                bfr[br] = *(const bf16x8*)&ww[cur][row][swz(row, kcol)];
            }
#pragma unroll
            for (int ar = 0; ar < 4; ++ar)
#pragma unroll
                for (int br = 0; br < 4; ++br)
                    acc[ar][br] = __builtin_amdgcn_mfma_f32_16x16x32_bf16(
                        af[ar], bfr[br], acc[ar][br], 0, 0, 0);
        }
        __syncthreads();
    }

    // epilogue: bf16 partial store
    unsigned short* po = pO + ((size_t)ks << 20);
    const int mrow = (lane >> 4) * 4;
#pragma unroll
    for (int ar = 0; ar < 4; ++ar) {
#pragma unroll
        for (int br = 0; br < 4; ++br) {
            int m = wr * 64 + ar * 16 + mrow;
            int n = n0 + wc * 64 + br * 16 + arow;
            unsigned short* pp = po + (size_t)m * OUT_F + n;
#pragma unroll
            for (int j = 0; j < 4; ++j) pp[(size_t)j * OUT_F] = bf16r(acc[ar][br][j]);
        }
    }
}

// ---------------- kernel D: reduce bf16 partials + scale + lora + bias ----------------
// grid = 16 nb * 32 mg = 512 blocks; thread: 2 consecutive n, 4 m's
__global__ __launch_bounds__(256) void reduce_out(const unsigned short* __restrict__ pO,
                                                  const float* __restrict__ tB,
                                                  const float* __restrict__ scale,
                                                  const float* __restrict__ lora_A,
                                                  const float* __restrict__ bias,
                                                  float* __restrict__ out) {
    __shared__ float ts[4][RANK];
    int nb = blockIdx.x & 15, mg = blockIdx.x >> 4;
    int tid = threadIdx.x;
    int m0 = mg * 4;
    if (tid < 128) {
        int i = tid >> 5, r = tid & 31;
        float s = 0.f;
#pragma unroll
        for (int c = 0; c < LKC; ++c) s += tB[(c * N_TOK + m0 + i) * RANK + r];
        ts[i][r] = s;
    }
    __syncthreads();
    int n = nb * 512 + tid * 2;
    float sc0 = scale[n], sc1 = scale[n + 1];
    float bs0 = bias[n], bs1 = bias[n + 1];
    float4 a0[8], a1[8];
    const float4* ap0 = (const float4*)(lora_A + (size_t)n * RANK);
    const float4* ap1 = (const float4*)(lora_A + (size_t)(n + 1) * RANK);
#pragma unroll
    for (int q = 0; q < 8; ++q) { a0[q] = ap0[q]; a1[q] = ap1[q]; }
#pragma unroll
    for (int i = 0; i < 4; ++i) {
        int m = m0 + i;
        const unsigned short* pp = pO + (size_t)m * OUT_F + n;
        float s0 = 0.f, s1 = 0.f;
#pragma unroll
        for (int c = 0; c < KSPLIT; ++c) {
            uint32_t u = *(const uint32_t*)(pp + ((size_t)c << 20));
            s0 += __uint_as_float(u << 16);
            s1 += __uint_as_float(u & 0xFFFF0000u);
        }
        float l0 = 0.f, l1 = 0.f;
#pragma unroll
        for (int q = 0; q < 8; ++q) {
            float4 tv = *(const float4*)&ts[i][q * 4];
            l0 = fmaf(tv.x, a0[q].x, l0); l0 = fmaf(tv.y, a0[q].y, l0);
            l0 = fmaf(tv.z, a0[q].z, l0); l0 = fmaf(tv.w, a0[q].w, l0);
            l1 = fmaf(tv.x, a1[q].x, l1); l1 = fmaf(tv.y, a1[q].y, l1);
            l1 = fmaf(tv.z, a1[q].z, l1); l1 = fmaf(tv.w, a1[q].w, l1);
        }
        out[(size_t)m * OUT_F + n]     = fmaf(s0, sc0, l0 + bs0);
        out[(size_t)m * OUT_F + n + 1] = fmaf(s1, sc1, l1 + bs1);
    }
}

extern "C" void kernel_launch(void* const* d_in, const int* in_sizes, int n_in,
                              void* d_out, int out_size, void* d_ws, size_t ws_size,
                              hipStream_t stream) {
    const float* x      = (const float*)d_in[0];
    const int*   wp     = (const int*)d_in[1];   // uint8 input -> int32 on device
    const float* scale  = (const float*)d_in[2];
    const float* lora_A = (const float*)d_in[3];
    const float* lora_B = (const float*)d_in[4];
    const float* bias   = (const float*)d_in[5];
    float* out = (float*)d_out;

    char* ws = (char*)d_ws;
    unsigned short* xt = (unsigned short*)(ws + XB_OFF);
    float* tB = (float*)(ws + TB_OFF);
    unsigned short* pO = (unsigned short*)(ws + PO_OFF);

    cvt_x<<<512, 256, 0, stream>>>(x, xt);
    lora_t<<<N_TOK * LKC, 256, 0, stream>>>(x, lora_B, tB);
    ternary_gemm<<<(OUT_F / 128) * KSPLIT, 256, 0, stream>>>(xt, wp, pO);
    reduce_out<<<16 * 32, 256, 0, stream>>>(pO, tB, scale, lora_A, bias, out);
}